// Round 11
// baseline (75.491 us; speedup 1.0000x reference)
//
#include <hip/hip_runtime.h>
#include <hip/hip_bf16.h>

typedef __attribute__((ext_vector_type(8))) short        short8;
typedef __attribute__((ext_vector_type(8))) __bf16       bf16x8;
typedef __attribute__((ext_vector_type(4))) float        f32x4;
typedef __attribute__((ext_vector_type(4))) unsigned int u32x4;

#define NB 32
#define CI 64
#define H  128
#define W  128
#define OH 126
#define OW 126
#define HW (H*W)

// bf16 LDS tile, FULL 64 ci, single pass: [pix = r*66+col][64 ci][16B pad]
// RSTRIDE = 144 B/pix (128 data + 16 pad). b128 ops at stride 144:
// start dword = 36*pix + 4*hi (mod 32) -> bank-group (pix+hi) mod 8,
// 8 lanes/group over the 8 min clocks -> conflict-free (reads AND writes).
#define TCOLS 66
#define RSTRIDE 144
#define LDS_BYTES (6*TCOLS*RSTRIDE)   // 57024 B -> 2 blocks/CU

__device__ __forceinline__ unsigned int f2bf(float f) {
    unsigned int u = __builtin_bit_cast(unsigned int, f);
    u += 0x7fffu + ((u >> 16) & 1u);
    return u >> 16;
}

// packed f32x2 -> bf16x2 (RNE), 1 instruction
__device__ __forceinline__ unsigned int cvt_pk(float lo, float hi) {
    unsigned int r;
    asm("v_cvt_pk_bf16_f32 %0, %1, %2" : "=v"(r) : "v"(lo), "v"(hi));
    return r;
}

// tanh(x) = 1 - 2/(exp2(2*log2e*x)+1); exact at +/-inf, ~1e-7 abs err
__device__ __forceinline__ float fast_tanh(float x) {
    float e = __builtin_amdgcn_exp2f(x * 2.8853900817779268f);
    float r = __builtin_amdgcn_rcpf(e + 1.0f);
    return 1.0f - 2.0f * r;
}

// ---------------------------------------------------------------------------
// Pre-pass: weights (64,64,3,3) fp32 OIHW -> MFMA B-fragment order, bf16.
// flat elem idx = ((ks*4 + cf)*64 + lane)*8 + j
//   ks = 0..17: khw = ks>>1, ci-half = ks&1; cf = co quarter,
//   lane: co = cf*16 + (lane&15), ci = (ks&1)*32 + 8*(lane>>4) + j
// ---------------------------------------------------------------------------
__global__ void wxform(const float* __restrict__ w, unsigned short* __restrict__ ws) {
    int tid = blockIdx.x * 256 + threadIdx.x;
    if (tid >= 18*4*64*8) return;
    int j   = tid & 7;
    int l   = (tid >> 3) & 63;
    int cf  = (tid >> 9) & 3;
    int ks  = tid >> 11;
    int co  = cf*16 + (l & 15);
    int ci  = (ks & 1)*32 + ((l >> 4) << 3) + j;
    int khw = ks >> 1;               // kh*3+kw
    int kh  = khw / 3, kw = khw % 3;
    float v = w[co*(CI*9) + ci*9 + kh*3 + kw];
    ws[tid] = (unsigned short)f2bf(v);
}

// ---------------------------------------------------------------------------
// Main: implicit-GEMM conv + channel-min + tanh(tanh()).
// 512-thread block (8 waves); wave wv = (row wv>>1, col-half wv&1):
// acc shrinks 64 -> 32 regs -> fits the 128-reg cap at 4 waves/EU, no spill.
// Single-pass full-ci LDS (57 KB, 2 blocks/CU), one barrier, conflict-free
// stride-144 layout.
// ---------------------------------------------------------------------------
__global__ __launch_bounds__(512, 4)
void conv_min_tanh(const float* __restrict__ x,
                   const unsigned short* __restrict__ wfrag,
                   const float* __restrict__ bias,
                   float* __restrict__ out) {
    __shared__ __align__(16) char xs[LDS_BYTES];

    const int lane = threadIdx.x & 63;
    const int wv   = threadIdx.x >> 6;   // 0..7
    const int c0   = blockIdx.x * 64;    // ow base (0 or 64)
    const int r0   = blockIdx.y * 4;     // oh base
    const int b    = blockIdx.z;
    const float* xb = x + (size_t)b * CI * HW;

    const int lane_c = lane & 15;
    const int hi     = lane >> 4;

    // ---- stage full tile: 48 tasks = (row 0..5) x (ci-oct 0..7) ----
    // Each lane: 8 plane loads -> 4 cvt_pk -> ONE ds_write_b128.
    #pragma unroll
    for (int i = 0; i < 6; ++i) {
        const int task = wv + 8*i;          // 0..47
        const int r    = task >> 3;         // 0..5
        const int q    = task & 7;          // ci oct
        const int gr   = r0 + r;
        float f0=0.f,f1=0.f,f2=0.f,f3=0.f,f4=0.f,f5=0.f,f6=0.f,f7=0.f;
        if (gr < H) {                        // wave-uniform; zero-fill OOB
            const float* xp = xb + (size_t)(q*8)*HW + gr*W + c0 + lane;
            f0 = xp[0];    f1 = xp[HW];   f2 = xp[2*HW]; f3 = xp[3*HW];
            f4 = xp[4*HW]; f5 = xp[5*HW]; f6 = xp[6*HW]; f7 = xp[7*HW];
        }
        u32x4 pk;
        pk.x = cvt_pk(f0, f1); pk.y = cvt_pk(f2, f3);
        pk.z = cvt_pk(f4, f5); pk.w = cvt_pk(f6, f7);
        *(u32x4*)(xs + (r*TCOLS + lane)*RSTRIDE + q*16) = pk;
    }
    // halo cols 64,65: threads 0..95 -> (row 0..5) x (col 2) x (oct 8)
    if (threadIdx.x < 96) {
        const int r  = threadIdx.x >> 4;     // 0..5
        const int sub = threadIdx.x & 15;
        const int cc = sub >> 3;             // 0..1
        const int q  = sub & 7;              // 0..7
        const int gr = r0 + r;
        const int gc = c0 + 64 + cc;
        float f0=0.f,f1=0.f,f2=0.f,f3=0.f,f4=0.f,f5=0.f,f6=0.f,f7=0.f;
        if (gr < H && gc < W) {              // zero-fill OOB
            const float* xq = xb + (size_t)(q*8)*HW + gr*W + gc;
            f0 = xq[0];    f1 = xq[HW];   f2 = xq[2*HW]; f3 = xq[3*HW];
            f4 = xq[4*HW]; f5 = xq[5*HW]; f6 = xq[6*HW]; f7 = xq[7*HW];
        }
        u32x4 pk;
        pk.x = cvt_pk(f0, f1); pk.y = cvt_pk(f2, f3);
        pk.z = cvt_pk(f4, f5); pk.w = cvt_pk(f6, f7);
        *(u32x4*)(xs + (r*TCOLS + 64 + cc)*RSTRIDE + q*16) = pk;
    }
    __syncthreads();                         // the only barrier

    const int wr   = wv >> 1;                // output row within tile (0..3)
    const int ch   = wv & 1;                 // col half (0..1)
    const int orow = r0 + wr;
    if (orow >= OH) return;                  // wave-uniform, post-barrier

    const short8* wp = (const short8*)wfrag;

    f32x4 acc[2][4];
    #pragma unroll
    for (int m = 0; m < 2; ++m)
        #pragma unroll
        for (int cf = 0; cf < 4; ++cf)
            acc[m][cf] = (f32x4){0.f, 0.f, 0.f, 0.f};

    // A-read base; khw/m/cih offsets are compile-time immediates (max 21664)
    const int abase = (wr*TCOLS + ch*32 + lane_c)*RSTRIDE + hi*16;

    short8 wfb[2][4];
    #pragma unroll
    for (int cf = 0; cf < 4; ++cf)           // ks = 0
        wfb[0][cf] = wp[cf*64 + lane];

    #pragma unroll
    for (int ks = 0; ks < 18; ++ks) {        // ks = khw*2 + cih
        const int buf = ks & 1;
        if (ks < 17) {                       // prefetch next ks
            #pragma unroll
            for (int cf = 0; cf < 4; ++cf)
                wfb[buf^1][cf] = wp[((ks+1)*4 + cf)*64 + lane];
        }
        const int khw = ks >> 1, cih = ks & 1;
        const int kh = khw/3, kw = khw%3;
        #pragma unroll
        for (int m = 0; m < 2; ++m) {
            const short8 av = *(const short8*)(
                xs + abase + kh*(TCOLS*RSTRIDE) + (kw + m*16)*RSTRIDE + cih*64);
            const bf16x8 a = __builtin_bit_cast(bf16x8, av);
            #pragma unroll
            for (int cf = 0; cf < 4; ++cf)
                acc[m][cf] = __builtin_amdgcn_mfma_f32_16x16x32_bf16(
                    a, __builtin_bit_cast(bf16x8, wfb[buf][cf]), acc[m][cf], 0, 0, 0);
        }
    }

    // ---- epilogue: +bias, min over 64 co, tanh(tanh()), store ----
    const float bs0 = bias[lane_c], bs1 = bias[16 + lane_c],
                bs2 = bias[32 + lane_c], bs3 = bias[48 + lane_c];
    float* outp = out + (b*OH + orow)*OW;
    #pragma unroll
    for (int m = 0; m < 2; ++m) {
        #pragma unroll
        for (int rg = 0; rg < 4; ++rg) {
            float v0 = fminf(fminf(acc[m][0][rg] + bs0, acc[m][1][rg] + bs1),
                             fminf(acc[m][2][rg] + bs2, acc[m][3][rg] + bs3));
            v0 = fminf(v0, __shfl_xor(v0, 1));
            v0 = fminf(v0, __shfl_xor(v0, 2));
            v0 = fminf(v0, __shfl_xor(v0, 4));
            v0 = fminf(v0, __shfl_xor(v0, 8));
            const float vt = fast_tanh(fast_tanh(v0));
            const int ocol = c0 + ch*32 + m*16 + hi*4 + rg;
            if (lane_c == 0 && ocol < OW) outp[ocol] = vt;
        }
    }
}

extern "C" void kernel_launch(void* const* d_in, const int* in_sizes, int n_in,
                              void* d_out, int out_size, void* d_ws, size_t ws_size,
                              hipStream_t stream) {
    const float* x    = (const float*)d_in[0];
    const float* w    = (const float*)d_in[1];
    const float* bias = (const float*)d_in[2];
    float* out        = (float*)d_out;
    unsigned short* wbuf = (unsigned short*)d_ws;   // needs 73728 B

    wxform<<<dim3(144), dim3(256), 0, stream>>>(w, wbuf);
    conv_min_tanh<<<dim3(2, 32, NB), dim3(512), 0, stream>>>(x, wbuf, bias, out);
}